// Round 13
// baseline (204.724 us; speedup 1.0000x reference)
//
#include <hip/hip_runtime.h>
#include <math.h>

#define BATCH 256
#define CIN   512
#define CP    256
#define HW    361
#define NOUT  6
#define NT    6      // hw tiles of 64

typedef short bf16x8 __attribute__((ext_vector_type(8)));
typedef float f32x4  __attribute__((ext_vector_type(4)));

__device__ __forceinline__ short f2bf(float f) {
    unsigned u = __float_as_uint(f);
    u += 0x7fffu + ((u >> 16) & 1u);
    return (short)(u >> 16);
}
__device__ __forceinline__ float bf2f(short s) {
    return __uint_as_float(((unsigned)(unsigned short)s) << 16);
}
// fast mish: mish(x) = x*(w-1)/(w+1), w=(1+e^x)^2.  Guard x>30 -> x (w overflow).
__device__ __forceinline__ float mish_f(float v) {
    float u = __expf(v);
    float a = 1.f + u;
    float w = a * a;
    float r = v * (w - 1.f) * __builtin_amdgcn_rcpf(w + 1.f);
    return (v > 30.f) ? v : r;
}

// ---------------------------------------------------------------------------
// K0: weights f32 -> bf16, plain row-major [row512][k512] (rows 0-255 = w1p,
// 256-511 = w1g). Consumed directly as MFMA A-fragments (16B/lane from L2).
// 32768 chunks of 16B: row = g>>6, chunk = g&63.
// ---------------------------------------------------------------------------
__global__ __launch_bounds__(256) void k0_weights(
    const float* __restrict__ w1p, const float* __restrict__ w1g,
    short* __restrict__ wT)
{
    int g = blockIdx.x * 256 + threadIdx.x;   // 0..32767
    int row = g >> 6;
    int ck  = g & 63;
    const float* src = (row < 256) ? (w1p + (size_t)row * CIN)
                                   : (w1g + (size_t)(row - 256) * CIN);
    int c = ck * 8;
    float f[8];
    *(float4*)(f)     = *(const float4*)(src + c);
    *(float4*)(f + 4) = *(const float4*)(src + c + 4);
    bf16x8 v;
    #pragma unroll
    for (int i = 0; i < 8; ++i) v[i] = f2bf(f[i]);
    *(bf16x8*)((char*)wT + (size_t)row * 1024 + ck * 16) = v;
}

// ---------------------------------------------------------------------------
// K1: fused transpose + conv1p + conv1g bf16 MFMA GEMM — A-direct-from-L2.
// Block = (b, n-tile of 64 hw): M=512 (both convs) x N=64, BK=64, 8 phases.
// 8 waves, each 64(M)x64(N): waves 0-3 conv1p rows, 4-7 conv1g rows; each
// wave's A-rows are PRIVATE -> A-fragments loaded straight from L2-resident
// wT (contiguous 16B/lane, no LDS, no staging, no barrier dependency).
// LDS holds only B: [64 hw][64 k] bf16 = 8KB x 2 buffers, 8-slot XOR swizzle
// (slot = q ^ ((row>>1)&7)) -> conflict-free ds_write_b128 and ds_read_b128.
// Phase: {BLOAD(t+1) 8xf32; bF-h0 ds_read; MFMA h0; aF-h1 load; bF-h1;
//         MFMA h1; BWRITE(t+1); aF(t+1)-h0 load; lgkmcnt(0); s_barrier}.
// Compiler's fine-grained waitcnts order the register deps; LDS ~18KB,
// 2 blocks/CU. Grid 1536, XCD-bijective remap.
// ---------------------------------------------------------------------------
__global__ __launch_bounds__(512, 4) void k1_conv1(
    const float* __restrict__ x, const short* __restrict__ wT,
    const float* __restrict__ mask, const float* __restrict__ beta_g,
    short* __restrict__ outp_pre, float* __restrict__ psum, float* __restrict__ pmax)
{
    int orig = blockIdx.x;
    int newid = (orig & 7) * 192 + (orig >> 3);   // 1536 = 8*192, bijective
    int n = newid % NT;
    int b = newid / NT;

    const int tid = threadIdx.x;
    const int lane = tid & 63, wid = tid >> 6;
    const int lc = lane & 15, lg = lane >> 4;
    const int hw0 = n * 64;

    __shared__ __align__(16) short Bs[2][4096];   // 2 x 8KB [row64][128B]
    __shared__ float maskS[64];
    __shared__ float betaS[256];

    if (tid < 64) {
        int hwg_ = hw0 + tid;
        maskS[tid] = (hwg_ < HW) ? mask[b * HW + hwg_] : 0.f;
    }
    if (tid < 256) betaS[tid] = beta_g[tid];

    // ---- B staging: thread owns (hw=brow, k-octet q). 8 f32 per phase.
    const int brow = tid & 63;
    const int q    = tid >> 6;             // 0..7
    const int hwg  = hw0 + brow;
    const bool bvalid = hwg < HW;
    const float* xq = x + ((size_t)b * CIN + q * 8) * HW + hwg;
    const int bDstOff = brow * 128 + ((q ^ ((brow >> 1) & 7)) * 16);
    char* bDstBase = (char*)Bs;

    // ---- A-direct addressing: lane (lc,lg) of wave wid, frag (mf,kb,kh):
    // row = wid*64 + mf*16 + lc ; k = kb*64 + kh*32 + lg*8  (16B contiguous)
    const char* aBase = (const char*)wT + (size_t)(wid * 64 + lc) * 1024 + lg * 16;

    // ---- B read offsets: frag (nf, kh): row r = nf*16+lc, slot = kh*4+lg
    int bOff[4][2];
    #pragma unroll
    for (int nf = 0; nf < 4; ++nf) {
        int r = nf * 16 + lc;
        #pragma unroll
        for (int kh = 0; kh < 2; ++kh)
            bOff[nf][kh] = r * 128 + (((kh * 4 + lg) ^ ((r >> 1) & 7)) * 16);
    }

    float regB[8];
    #pragma unroll
    for (int i = 0; i < 8; ++i) regB[i] = 0.f;

    f32x4 acc[4][4];
    #pragma unroll
    for (int i = 0; i < 4; ++i)
        #pragma unroll
        for (int j = 0; j < 4; ++j)
            acc[i][j] = (f32x4){0.f, 0.f, 0.f, 0.f};

#define BLOAD(kb)                                                          \
    do {                                                                   \
        const float* src_ = xq + (size_t)(kb) * 64 * HW;                   \
        _Pragma("unroll")                                                  \
        for (int i_ = 0; i_ < 8; ++i_)                                     \
            regB[i_] = bvalid ? src_[(size_t)i_ * HW] : 0.f;               \
    } while (0)

#define BWRITE(buf)                                                        \
    do {                                                                   \
        bf16x8 o_;                                                         \
        _Pragma("unroll")                                                  \
        for (int i_ = 0; i_ < 8; ++i_) o_[i_] = f2bf(regB[i_]);            \
        *(bf16x8*)(bDstBase + (buf) * 8192 + bDstOff) = o_;                \
    } while (0)

#define ALOAD(dst, kb, kh)                                                 \
    do {                                                                   \
        _Pragma("unroll")                                                  \
        for (int mf_ = 0; mf_ < 4; ++mf_)                                  \
            dst[mf_] = *(const bf16x8*)(aBase + mf_ * 16384 +              \
                                        (kb) * 128 + (kh) * 64);           \
    } while (0)

#define MFMA_HALF(af, buf, kh)                                             \
    do {                                                                   \
        bf16x8 bF_[4];                                                     \
        _Pragma("unroll")                                                  \
        for (int nf_ = 0; nf_ < 4; ++nf_)                                  \
            bF_[nf_] = *(const bf16x8*)((const char*)Bs + (buf) * 8192 +   \
                                        bOff[nf_][kh]);                    \
        __builtin_amdgcn_s_setprio(1);                                     \
        _Pragma("unroll")                                                  \
        for (int mf_ = 0; mf_ < 4; ++mf_)                                  \
            _Pragma("unroll")                                              \
            for (int nf_ = 0; nf_ < 4; ++nf_)                              \
                acc[mf_][nf_] = __builtin_amdgcn_mfma_f32_16x16x32_bf16(   \
                    af[mf_], bF_[nf_], acc[mf_][nf_], 0, 0, 0);            \
        __builtin_amdgcn_s_setprio(0);                                     \
    } while (0)

    // ---- prologue: stage B(0), prefetch B(1) regs, preload aF(0,h0)
    bf16x8 aF0[4], aF1[4];
    BLOAD(0);
    BWRITE(0);                    // compiler waits regB
    BLOAD(1);
    ALOAD(aF0, 0, 0);
    __syncthreads();              // B(0) visible

    #pragma unroll
    for (int t = 0; t < 8; ++t) {
        const int buf = t & 1;
        if (t < 7) { /* B(t+1) already in regB */ }
        MFMA_HALF(aF0, buf, 0);           // h0: aF0 preloaded
        ALOAD(aF1, t, 1);                 // h1 frags (L2, ~300cy under h0 tail)
        MFMA_HALF(aF1, buf, 1);           // h1
        if (t < 7) {
            BWRITE((t + 1) & 1);          // compiler waits regB(t+1)
            if (t < 6) BLOAD(t + 2);      // refill regB for next phase
            ALOAD(aF0, t + 1, 0);         // next-phase h0 frags
            asm volatile("s_waitcnt lgkmcnt(0)" ::: "memory");
            __builtin_amdgcn_sched_barrier(0);
            __builtin_amdgcn_s_barrier();
            __builtin_amdgcn_sched_barrier(0);
        }
    }

    // ---- epilogue: barrier-free, waves independent
    if (wid < 4) {
        // conv1p rows 0..255: store pre-activation bf16
        #pragma unroll
        for (int mf = 0; mf < 4; ++mf) {
            int ch = wid * 64 + mf * 16 + lg * 4;
            #pragma unroll
            for (int nf = 0; nf < 4; ++nf) {
                int hw = hw0 + nf * 16 + lc;
                if (hw < HW) {
                    #pragma unroll
                    for (int j = 0; j < 4; ++j)
                        outp_pre[((size_t)(b * CP + ch + j)) * HW + hw] = f2bf(acc[mf][nf][j]);
                }
            }
        }
    } else {
        // conv1g rows: mish((acc+beta)*mask); intra-wave sum/max over 64 hw
        #pragma unroll
        for (int mf = 0; mf < 4; ++mf) {
            #pragma unroll
            for (int j = 0; j < 4; ++j) {
                int rloc = (wid - 4) * 64 + mf * 16 + lg * 4 + j;   // 0..255
                float beta = betaS[rloc];
                float s = 0.f, mx = -INFINITY;
                #pragma unroll
                for (int nf = 0; nf < 4; ++nf) {
                    int cl = nf * 16 + lc;
                    int hw = hw0 + cl;
                    float mv = maskS[cl];
                    float val = mish_f((acc[mf][nf][j] + beta) * mv);
                    if (hw < HW) {
                        s += val * mv;
                        mx = fmaxf(mx, val + mv - 1.f);
                    }
                }
                #pragma unroll
                for (int off = 1; off < 16; off <<= 1) {
                    s += __shfl_xor(s, off, 64);
                    mx = fmaxf(mx, __shfl_xor(mx, off, 64));
                }
                if (lc == 0) {
                    psum[((size_t)(b * CP + rloc)) * NT + n] = s;
                    pmax[((size_t)(b * CP + rloc)) * NT + n] = mx;
                }
            }
        }
    }
#undef BLOAD
#undef BWRITE
#undef ALOAD
#undef MFMA_HALF
}

// ---------------------------------------------------------------------------
// K2: per-batch pooled vector + linear_g. Grid 256 blocks x 256 threads.
// ---------------------------------------------------------------------------
__global__ __launch_bounds__(256) void k2_pool_linear(
    const float* __restrict__ mask, const float* __restrict__ psum,
    const float* __restrict__ pmax, const float* __restrict__ lw,
    float* __restrict__ g_out)
{
    int b = blockIdx.x, t = threadIdx.x;
    __shared__ float pooled[768];
    __shared__ float msr[4];

    float s = 0.f;
    for (int i = t; i < HW; i += 256) s += mask[b * HW + i];
    #pragma unroll
    for (int off = 1; off < 64; off <<= 1) s += __shfl_xor(s, off, 64);
    if ((t & 63) == 0) msr[t >> 6] = s;
    __syncthreads();
    float msum = msr[0] + msr[1] + msr[2] + msr[3];

    {
        int c = t;
        const float* ps = psum + (size_t)(b * CP + c) * NT;
        const float* pm = pmax + (size_t)(b * CP + c) * NT;
        float s3 = 0.f, m3 = -INFINITY;
        #pragma unroll
        for (int i = 0; i < NT; ++i) { s3 += ps[i]; m3 = fmaxf(m3, pm[i]); }
        float mean = s3 / msum;
        float sq = (sqrtf(msum) - 14.f) * 0.1f;
        pooled[c] = mean; pooled[256 + c] = mean * sq; pooled[512 + c] = m3;
    }
    __syncthreads();
    {
        int o = t;
        const float4* wrow = (const float4*)(lw + (size_t)o * 768);
        float acc = 0.f;
        #pragma unroll 8
        for (int j = 0; j < 192; ++j) {
            float4 w4 = wrow[j];
            float4 p4 = *(const float4*)&pooled[j * 4];
            acc += p4.x * w4.x + p4.y * w4.y + p4.z * w4.z + p4.w * w4.w;
        }
        g_out[b * CP + o] = acc;
    }
}

// ---------------------------------------------------------------------------
// K3: final fused mish((outp_pre+g+beta2)*mask) -> conv2p -> mask bias.
// outp_pre is bf16. Grid (6 hw-tiles, 256 b) x 256 threads.
// ---------------------------------------------------------------------------
__global__ __launch_bounds__(256) void k3_final(
    const short* __restrict__ outp_pre, const float* __restrict__ mask,
    const float* __restrict__ g_out, const float* __restrict__ beta2,
    const float* __restrict__ w2, float* __restrict__ out)
{
    int ht = blockIdx.x, b = blockIdx.y;
    int t = threadIdx.x;
    __shared__ float w2S[NOUT * 256];
    __shared__ float gbS[256];
    __shared__ float part[NOUT][256];

    for (int i = t; i < NOUT * 256; i += 256) w2S[i] = w2[i];
    gbS[t] = g_out[b * CP + t] + beta2[t];
    __syncthreads();

    int hw = t & 63, cg = t >> 6;
    int hwg = ht * 64 + hw;
    bool valid = hwg < HW;
    float maskv = valid ? mask[b * HW + hwg] : 0.f;

    float acc[NOUT] = {0.f, 0.f, 0.f, 0.f, 0.f, 0.f};
    const short* src = outp_pre + ((size_t)(b * CP + cg * 64)) * HW + hwg;
    #pragma unroll 4
    for (int ci = 0; ci < 64; ++ci) {
        float v = valid ? bf2f(src[(size_t)ci * HW]) : 0.f;
        float mm = mish_f((v + gbS[cg * 64 + ci]) * maskv);
        #pragma unroll
        for (int o = 0; o < NOUT; ++o) acc[o] += mm * w2S[o * 256 + cg * 64 + ci];
    }
    #pragma unroll
    for (int o = 0; o < NOUT; ++o) part[o][t] = acc[o];
    __syncthreads();

    for (int idx = t; idx < NOUT * 64; idx += 256) {
        int o = idx >> 6, h2 = idx & 63;
        int hg = ht * 64 + h2;
        if (hg < HW) {
            float mv = mask[b * HW + hg];
            float sum = part[o][h2] + part[o][64 + h2] + part[o][128 + h2] + part[o][192 + h2];
            out[((size_t)(b * NOUT + o)) * HW + hg] = sum - (1.f - mv) * 5000.f;
        }
    }
}

extern "C" void kernel_launch(void* const* d_in, const int* in_sizes, int n_in,
                              void* d_out, int out_size, void* d_ws, size_t ws_size,
                              hipStream_t stream) {
    const float* x     = (const float*)d_in[0];
    const float* mask  = (const float*)d_in[1];
    const float* w1p   = (const float*)d_in[2];
    const float* w1g   = (const float*)d_in[3];
    const float* betag = (const float*)d_in[4];
    const float* lw    = (const float*)d_in[5];
    const float* beta2 = (const float*)d_in[6];
    const float* w2    = (const float*)d_in[7];
    float* out = (float*)d_out;

    char* ws = (char*)d_ws;
    short* outp_pre = (short*)(ws);                      // 256*256*361*2 = 47,316,992 B
    short* wT       = (short*)(ws + 47316992);           // 512*1024      =     524,288 B
    float* psum     = (float*)(ws + 47841280);           // 256*256*6*4   =   1,572,864 B
    float* pmax     = (float*)(ws + 49414144);           // 256*256*6*4   =   1,572,864 B
    float* g_out    = (float*)(ws + 50987008);           // 256*256*4     =     262,144 B

    hipLaunchKernelGGL(k0_weights, dim3(128), dim3(256), 0, stream, w1p, w1g, wT);
    hipLaunchKernelGGL(k1_conv1, dim3(1536), dim3(512), 0, stream,
                       x, wT, mask, betag, outp_pre, psum, pmax);
    hipLaunchKernelGGL(k2_pool_linear, dim3(BATCH), dim3(256), 0, stream,
                       mask, psum, pmax, lw, g_out);
    hipLaunchKernelGGL(k3_final, dim3(6, BATCH), dim3(256), 0, stream,
                       outp_pre, mask, g_out, beta2, w2, out);
    (void)in_sizes; (void)n_in; (void)out_size; (void)ws_size;
}

// Round 14
// 168.286 us; speedup vs baseline: 1.2165x; 1.2165x over previous
//
#include <hip/hip_runtime.h>
#include <math.h>

#define BATCH 256
#define CIN   512
#define CP    256
#define HW    361
#define NOUT  6
#define NT    6      // hw tiles of 64

typedef short bf16x8 __attribute__((ext_vector_type(8)));
typedef short bf16x4 __attribute__((ext_vector_type(4)));
typedef float f32x4  __attribute__((ext_vector_type(4)));

__device__ __forceinline__ short f2bf(float f) {
    unsigned u = __float_as_uint(f);
    u += 0x7fffu + ((u >> 16) & 1u);
    return (short)(u >> 16);
}
__device__ __forceinline__ float bf2f(short s) {
    return __uint_as_float(((unsigned)(unsigned short)s) << 16);
}
// fast mish: mish(x) = x*(w-1)/(w+1), w=(1+e^x)^2.  Guard x>30 -> x (w overflow).
__device__ __forceinline__ float mish_f(float v) {
    float u = __expf(v);
    float a = 1.f + u;
    float w = a * a;
    float r = v * (w - 1.f) * __builtin_amdgcn_rcpf(w + 1.f);
    return (v > 30.f) ? v : r;
}

// ---------------------------------------------------------------------------
// K0: weights f32 -> bf16, fragment-major [kb16][row512][lg4][16B]:
// chunk (kb,row,lg) holds k = kb*32 + lg*8 .. +7 of row. A wave's 4-frag
// phase load (lanes lc=row%16... wid*64+mf*16+lc rows, lg chunks) is then
// 64 consecutive 16B chunks = 1KB contiguous -> perfectly coalesced L2 read.
// ---------------------------------------------------------------------------
__global__ __launch_bounds__(256) void k0_weights(
    const float* __restrict__ w1p, const float* __restrict__ w1g,
    short* __restrict__ wT)
{
    int g = blockIdx.x * 256 + threadIdx.x;   // 0..32767 chunk id
    int kb  = g >> 11;                        // 0..15
    int row = (g >> 2) & 511;                 // 0..511
    int lg  = g & 3;                          // 0..3
    const float* src = (row < 256) ? (w1p + (size_t)row * CIN)
                                   : (w1g + (size_t)(row - 256) * CIN);
    int c = kb * 32 + lg * 8;
    float f[8];
    *(float4*)(f)     = *(const float4*)(src + c);
    *(float4*)(f + 4) = *(const float4*)(src + c + 4);
    bf16x8 v;
    #pragma unroll
    for (int i = 0; i < 8; ++i) v[i] = f2bf(f[i]);
    // layout: [kb][row/16 grp][lg? no] -- frag-major: ((kb*512 + row)*4 + lg)
    *(bf16x8*)((char*)wT + (((size_t)kb * 512 + row) * 4 + lg) * 16) = v;
}

// ---------------------------------------------------------------------------
// K1: fused transpose + conv1p + conv1g bf16 MFMA GEMM — A-in-registers.
// Block = (b, n-tile of 64 hw): M=512 (both convs) x N=64, BK=32, 16 phases.
// 8 waves, each 64(M)x64(N), A-rows wave-private -> A-fragments live in a
// REGISTER double-buffer aR[2][4] (32 VGPR), loaded from L2-resident wT with
// one-full-phase lookahead (phase t issues A(t+1) at top, consumes A(t)).
// LDS holds only B (r12's proven path, byte-identical): 2 x 4KB buffers,
// deep-B: all 512 threads stage 4 f32 at depth 2, swizzled ds_write_b64.
// All load waits compiler-managed (register deps); manual sync is only
// lgkmcnt(0) + s_barrier per phase (ds_write visibility; vmcnt NOT drained,
// so A/B loads stay in flight across barriers).
// LDS ~10KB; VGPR-capped at 4 waves/SIMD -> 2 blocks/CU. Grid 1536, XCD remap.
// ---------------------------------------------------------------------------
__global__ __launch_bounds__(512, 4) void k1_conv1(
    const float* __restrict__ x, const short* __restrict__ wT,
    const float* __restrict__ mask, const float* __restrict__ beta_g,
    short* __restrict__ outp_pre, float* __restrict__ psum, float* __restrict__ pmax)
{
    int orig = blockIdx.x;
    int newid = (orig & 7) * 192 + (orig >> 3);   // 1536 = 8*192, bijective
    int n = newid % NT;
    int b = newid / NT;

    const int tid = threadIdx.x;
    const int lane = tid & 63, wid = tid >> 6;
    const int lc = lane & 15, lg = lane >> 4;
    const int hw0 = n * 64;

    __shared__ __align__(16) short Bs[2][2048];   // 2 x 4KB [row64][64B]
    __shared__ float maskS[64];
    __shared__ float betaS[256];

    if (tid < 64) {
        int hwg_ = hw0 + tid;
        maskS[tid] = (hwg_ < HW) ? mask[b * HW + hwg_] : 0.f;
    }
    if (tid < 256) betaS[tid] = beta_g[tid];

    // ---- B duty (ALL 512 threads): thread owns (hw=brow, c-quad q).
    // Byte layout in LDS identical to r11/r12: slot=(q>>1)^((brow>>1)&3), half=q&1.
    const int brow = tid & 63;
    const int q    = tid >> 6;             // 0..7 (c-quad)
    const int hwg  = hw0 + brow;
    const bool bvalid = hwg < HW;
    const float* xq = x + ((size_t)b * CIN + q * 4) * HW + hwg;
    const int bDstOff = brow * 64 + (((q >> 1) ^ ((brow >> 1) & 3)) * 16) + ((q & 1) * 8);
    char* bDstBase = (char*)Bs;

    // ---- A-in-reg addressing: frag (mf, kb): chunk = ((kb*512 + wid*64+mf*16+lc)*4 + lg)
    const char* aBase = (const char*)wT + ((size_t)(wid * 64 + lc) * 4 + lg) * 16;

    // ---- B read offsets (r12 pattern): frag nf: row r = nf*16+lc
    int bOff[4];
    #pragma unroll
    for (int nf = 0; nf < 4; ++nf) {
        int r = nf * 16 + lc;                      // 0..63
        bOff[nf] = r * 64 + ((lg ^ ((r >> 1) & 3)) * 16);
    }

    float regB[2][4];
    #pragma unroll
    for (int i = 0; i < 4; ++i) { regB[0][i] = 0.f; regB[1][i] = 0.f; }

    bf16x8 aR[2][4];
    f32x4 acc[4][4];
    #pragma unroll
    for (int i = 0; i < 4; ++i)
        #pragma unroll
        for (int j = 0; j < 4; ++j)
            acc[i][j] = (f32x4){0.f, 0.f, 0.f, 0.f};

#define BLOAD(SET, kb)                                                     \
    do {                                                                   \
        const float* src_ = xq + (size_t)(kb) * 32 * HW;                   \
        _Pragma("unroll")                                                  \
        for (int i_ = 0; i_ < 4; ++i_)                                     \
            regB[SET][i_] = bvalid ? src_[(size_t)i_ * HW] : 0.f;          \
    } while (0)

#define BWRITE(SET, buf)                                                   \
    do {                                                                   \
        bf16x4 o_;                                                         \
        _Pragma("unroll")                                                  \
        for (int i_ = 0; i_ < 4; ++i_) o_[i_] = f2bf(regB[SET][i_]);       \
        *(bf16x4*)(bDstBase + (buf) * 4096 + bDstOff) = o_;                \
    } while (0)

#define ALOADR(SET, kb)                                                    \
    do {                                                                   \
        _Pragma("unroll")                                                  \
        for (int mf_ = 0; mf_ < 4; ++mf_)                                  \
            aR[SET][mf_] = *(const bf16x8*)(aBase +                        \
                ((size_t)(kb) * 512 + mf_ * 16) * 64);                     \
    } while (0)

    // ---- prologue: A(0) into set 0; B(0) staged; B(1) in regs
    ALOADR(0, 0);
    BLOAD(0, 0);
    BWRITE(0, 0);                 // compiler waits regB[0]
    BLOAD(1, 1);
    __syncthreads();              // B(0) visible (prologue full drain is fine)

    #pragma unroll
    for (int t = 0; t < 16; ++t) {
        const int p  = t & 1;          // A reg set + B LDS buffer for phase t
        const int np = p ^ 1;

        if (t < 15) ALOADR(np, t + 1);     // A(t+1): fire-and-forget, used next phase
        if (t < 14) BLOAD(p, t + 2);       // B(t+2) f32 regs (depth 2)

        bf16x8 bF[4];
        #pragma unroll
        for (int nf = 0; nf < 4; ++nf)
            bF[nf] = *(const bf16x8*)((const char*)Bs + p * 4096 + bOff[nf]);

        __builtin_amdgcn_s_setprio(1);
        #pragma unroll
        for (int mf = 0; mf < 4; ++mf)
            #pragma unroll
            for (int nf = 0; nf < 4; ++nf)
                acc[mf][nf] = __builtin_amdgcn_mfma_f32_16x16x32_bf16(
                    aR[p][mf], bF[nf], acc[mf][nf], 0, 0, 0);
        __builtin_amdgcn_s_setprio(0);

        if (t < 15) {
            BWRITE(np, np);                // compiler waits regB(t+1) only
            asm volatile("s_waitcnt lgkmcnt(0)" ::: "memory");
            __builtin_amdgcn_sched_barrier(0);
            __builtin_amdgcn_s_barrier();
            __builtin_amdgcn_sched_barrier(0);
        }
    }

    // ---- epilogue: barrier-free, waves independent
    if (wid < 4) {
        // conv1p rows 0..255: store pre-activation bf16
        #pragma unroll
        for (int mf = 0; mf < 4; ++mf) {
            int ch = wid * 64 + mf * 16 + lg * 4;
            #pragma unroll
            for (int nf = 0; nf < 4; ++nf) {
                int hw = hw0 + nf * 16 + lc;
                if (hw < HW) {
                    #pragma unroll
                    for (int j = 0; j < 4; ++j)
                        outp_pre[((size_t)(b * CP + ch + j)) * HW + hw] = f2bf(acc[mf][nf][j]);
                }
            }
        }
    } else {
        // conv1g rows: mish((acc+beta)*mask); intra-wave sum/max over 64 hw
        #pragma unroll
        for (int mf = 0; mf < 4; ++mf) {
            #pragma unroll
            for (int j = 0; j < 4; ++j) {
                int rloc = (wid - 4) * 64 + mf * 16 + lg * 4 + j;   // 0..255
                float beta = betaS[rloc];
                float s = 0.f, mx = -INFINITY;
                #pragma unroll
                for (int nf = 0; nf < 4; ++nf) {
                    int cl = nf * 16 + lc;
                    int hw = hw0 + cl;
                    float mv = maskS[cl];
                    float val = mish_f((acc[mf][nf][j] + beta) * mv);
                    if (hw < HW) {
                        s += val * mv;
                        mx = fmaxf(mx, val + mv - 1.f);
                    }
                }
                #pragma unroll
                for (int off = 1; off < 16; off <<= 1) {
                    s += __shfl_xor(s, off, 64);
                    mx = fmaxf(mx, __shfl_xor(mx, off, 64));
                }
                if (lc == 0) {
                    psum[((size_t)(b * CP + rloc)) * NT + n] = s;
                    pmax[((size_t)(b * CP + rloc)) * NT + n] = mx;
                }
            }
        }
    }
#undef BLOAD
#undef BWRITE
#undef ALOADR
}

// ---------------------------------------------------------------------------
// K2: per-batch pooled vector + linear_g. Grid 256 blocks x 256 threads.
// ---------------------------------------------------------------------------
__global__ __launch_bounds__(256) void k2_pool_linear(
    const float* __restrict__ mask, const float* __restrict__ psum,
    const float* __restrict__ pmax, const float* __restrict__ lw,
    float* __restrict__ g_out)
{
    int b = blockIdx.x, t = threadIdx.x;
    __shared__ float pooled[768];
    __shared__ float msr[4];

    float s = 0.f;
    for (int i = t; i < HW; i += 256) s += mask[b * HW + i];
    #pragma unroll
    for (int off = 1; off < 64; off <<= 1) s += __shfl_xor(s, off, 64);
    if ((t & 63) == 0) msr[t >> 6] = s;
    __syncthreads();
    float msum = msr[0] + msr[1] + msr[2] + msr[3];

    {
        int c = t;
        const float* ps = psum + (size_t)(b * CP + c) * NT;
        const float* pm = pmax + (size_t)(b * CP + c) * NT;
        float s3 = 0.f, m3 = -INFINITY;
        #pragma unroll
        for (int i = 0; i < NT; ++i) { s3 += ps[i]; m3 = fmaxf(m3, pm[i]); }
        float mean = s3 / msum;
        float sq = (sqrtf(msum) - 14.f) * 0.1f;
        pooled[c] = mean; pooled[256 + c] = mean * sq; pooled[512 + c] = m3;
    }
    __syncthreads();
    {
        int o = t;
        const float4* wrow = (const float4*)(lw + (size_t)o * 768);
        float acc = 0.f;
        #pragma unroll 8
        for (int j = 0; j < 192; ++j) {
            float4 w4 = wrow[j];
            float4 p4 = *(const float4*)&pooled[j * 4];
            acc += p4.x * w4.x + p4.y * w4.y + p4.z * w4.z + p4.w * w4.w;
        }
        g_out[b * CP + o] = acc;
    }
}

// ---------------------------------------------------------------------------
// K3: final fused mish((outp_pre+g+beta2)*mask) -> conv2p -> mask bias.
// outp_pre is bf16. Grid (6 hw-tiles, 256 b) x 256 threads.
// ---------------------------------------------------------------------------
__global__ __launch_bounds__(256) void k3_final(
    const short* __restrict__ outp_pre, const float* __restrict__ mask,
    const float* __restrict__ g_out, const float* __restrict__ beta2,
    const float* __restrict__ w2, float* __restrict__ out)
{
    int ht = blockIdx.x, b = blockIdx.y;
    int t = threadIdx.x;
    __shared__ float w2S[NOUT * 256];
    __shared__ float gbS[256];
    __shared__ float part[NOUT][256];

    for (int i = t; i < NOUT * 256; i += 256) w2S[i] = w2[i];
    gbS[t] = g_out[b * CP + t] + beta2[t];
    __syncthreads();

    int hw = t & 63, cg = t >> 6;
    int hwg = ht * 64 + hw;
    bool valid = hwg < HW;
    float maskv = valid ? mask[b * HW + hwg] : 0.f;

    float acc[NOUT] = {0.f, 0.f, 0.f, 0.f, 0.f, 0.f};
    const short* src = outp_pre + ((size_t)(b * CP + cg * 64)) * HW + hwg;
    #pragma unroll 4
    for (int ci = 0; ci < 64; ++ci) {
        float v = valid ? bf2f(src[(size_t)ci * HW]) : 0.f;
        float mm = mish_f((v + gbS[cg * 64 + ci]) * maskv);
        #pragma unroll
        for (int o = 0; o < NOUT; ++o) acc[o] += mm * w2S[o * 256 + cg * 64 + ci];
    }
    #pragma unroll
    for (int o = 0; o < NOUT; ++o) part[o][t] = acc[o];
    __syncthreads();

    for (int idx = t; idx < NOUT * 64; idx += 256) {
        int o = idx >> 6, h2 = idx & 63;
        int hg = ht * 64 + h2;
        if (hg < HW) {
            float mv = mask[b * HW + hg];
            float sum = part[o][h2] + part[o][64 + h2] + part[o][128 + h2] + part[o][192 + h2];
            out[((size_t)(b * NOUT + o)) * HW + hg] = sum - (1.f - mv) * 5000.f;
        }
    }
}

extern "C" void kernel_launch(void* const* d_in, const int* in_sizes, int n_in,
                              void* d_out, int out_size, void* d_ws, size_t ws_size,
                              hipStream_t stream) {
    const float* x     = (const float*)d_in[0];
    const float* mask  = (const float*)d_in[1];
    const float* w1p   = (const float*)d_in[2];
    const float* w1g   = (const float*)d_in[3];
    const float* betag = (const float*)d_in[4];
    const float* lw    = (const float*)d_in[5];
    const float* beta2 = (const float*)d_in[6];
    const float* w2    = (const float*)d_in[7];
    float* out = (float*)d_out;

    char* ws = (char*)d_ws;
    short* outp_pre = (short*)(ws);                      // 256*256*361*2 = 47,316,992 B
    short* wT       = (short*)(ws + 47316992);           // 16*512*64     =     524,288 B
    float* psum     = (float*)(ws + 47841280);           // 256*256*6*4   =   1,572,864 B
    float* pmax     = (float*)(ws + 49414144);           // 256*256*6*4   =   1,572,864 B
    float* g_out    = (float*)(ws + 50987008);           // 256*256*4     =     262,144 B

    hipLaunchKernelGGL(k0_weights, dim3(128), dim3(256), 0, stream, w1p, w1g, wT);
    hipLaunchKernelGGL(k1_conv1, dim3(1536), dim3(512), 0, stream,
                       x, wT, mask, betag, outp_pre, psum, pmax);
    hipLaunchKernelGGL(k2_pool_linear, dim3(BATCH), dim3(256), 0, stream,
                       mask, psum, pmax, lw, g_out);
    hipLaunchKernelGGL(k3_final, dim3(6, BATCH), dim3(256), 0, stream,
                       outp_pre, mask, g_out, beta2, w2, out);
    (void)in_sizes; (void)n_in; (void)out_size; (void)ws_size;
}

// Round 15
// 140.716 us; speedup vs baseline: 1.4549x; 1.1959x over previous
//
#include <hip/hip_runtime.h>
#include <math.h>

#define BATCH 256
#define CIN   512
#define CP    256
#define HW    361
#define NOUT  6
#define NT    6      // hw tiles of 64

typedef short bf16x8 __attribute__((ext_vector_type(8)));
typedef short bf16x4 __attribute__((ext_vector_type(4)));
typedef float f32x4  __attribute__((ext_vector_type(4)));

__device__ __forceinline__ short f2bf(float f) {
    unsigned u = __float_as_uint(f);
    u += 0x7fffu + ((u >> 16) & 1u);
    return (short)(u >> 16);
}
__device__ __forceinline__ float bf2f(short s) {
    return __uint_as_float(((unsigned)(unsigned short)s) << 16);
}
// fast mish: mish(x) = x*(w-1)/(w+1), w=(1+e^x)^2.  Guard x>30 -> x (w overflow).
__device__ __forceinline__ float mish_f(float v) {
    float u = __expf(v);
    float a = 1.f + u;
    float w = a * a;
    float r = v * (w - 1.f) * __builtin_amdgcn_rcpf(w + 1.f);
    return (v > 30.f) ? v : r;
}
__device__ __forceinline__ void gl_lds16(const void* g, void* l) {
    __builtin_amdgcn_global_load_lds(
        (const __attribute__((address_space(1))) void*)g,
        (__attribute__((address_space(3))) void*)l, 16, 0, 0);
}

// ---------------------------------------------------------------------------
// K0: weights f32 -> bf16, pre-swizzled [kb16][row512][slot4*16B].
// rows 0-255 = w1p, 256-511 = w1g. Dest slot s holds source chunk
// sc = s ^ ((row>>1)&3)  (consumed via lg ^ ((r>>1)&3) on the read side).
// ---------------------------------------------------------------------------
__global__ __launch_bounds__(256) void k0_weights(
    const float* __restrict__ w1p, const float* __restrict__ w1g,
    short* __restrict__ wT)
{
    int g = blockIdx.x * 256 + threadIdx.x;   // 0..32767 chunk id
    int kb  = g >> 11;
    int row = (g >> 2) & 511;
    int s   = g & 3;
    int sc  = s ^ ((row >> 1) & 3);
    const float* src = (row < 256) ? (w1p + (size_t)row * CIN)
                                   : (w1g + (size_t)(row - 256) * CIN);
    int c = kb * 32 + sc * 8;
    float f[8];
    *(float4*)(f)     = *(const float4*)(src + c);
    *(float4*)(f + 4) = *(const float4*)(src + c + 4);
    bf16x8 v;
    #pragma unroll
    for (int i = 0; i < 8; ++i) v[i] = f2bf(f[i]);
    *(bf16x8*)((char*)wT + (size_t)kb * 32768 + row * 64 + s * 16) = v;
}

// ---------------------------------------------------------------------------
// K1: fused transpose + conv1p + conv1g bf16 MFMA GEMM — fat-M, deep-B.
// Block = (b, n-tile of 64 hw): M=512 (both convs) x N=64, BK=32, 16 phases.
// 8 waves, each 64(M)x64(N): waves 0-3 conv1p rows, 4-7 conv1g rows.
// A: global_load_lds from pre-swizzled wT, 2 x 32KB buffers, depth 1 (L2-hot).
// B: ALL 512 threads stage 4 f32 each (coalesced over hw) at prefetch DEPTH 2
//    (BLOAD(t+2) issued in phase t) -> cvt -> swizzled ds_write_b64
//    (slot=(q>>1)^((brow>>1)&3), half=q&1), 2 x 4KB buffers.
// Phase: {8 ds_read frags; ALOAD(t+1); BLOAD(t+2); MFMA x16; vmcnt(4) ->
//         leaves only B(t+2) in flight; BWRITE(t+1); lgkmcnt(0); barrier}.
// LDS 73KB -> 2 blocks/CU. Grid 1536, XCD-bijective remap.
// Empirical best of 13 structural variants (r12: 142.07 us total).
// ---------------------------------------------------------------------------
__global__ __launch_bounds__(512, 4) void k1_conv1(
    const float* __restrict__ x, const short* __restrict__ wT,
    const float* __restrict__ mask, const float* __restrict__ beta_g,
    short* __restrict__ outp_pre, float* __restrict__ psum, float* __restrict__ pmax)
{
    int orig = blockIdx.x;
    int newid = (orig & 7) * 192 + (orig >> 3);   // 1536 = 8*192, bijective
    int n = newid % NT;
    int b = newid / NT;

    const int tid = threadIdx.x;
    const int lane = tid & 63, wid = tid >> 6;
    const int lc = lane & 15, lg = lane >> 4;
    const int hw0 = n * 64;

    __shared__ __align__(16) short As[2][16384];  // 2 x 32KB [row512][64B]
    __shared__ __align__(16) short Bs[2][2048];   // 2 x  4KB [row64][64B]
    __shared__ float maskS[64];
    __shared__ float betaS[256];

    if (tid < 64) {
        int hwg_ = hw0 + tid;
        maskS[tid] = (hwg_ < HW) ? mask[b * HW + hwg_] : 0.f;
    }
    if (tid < 256) betaS[tid] = beta_g[tid];
    asm volatile("s_waitcnt vmcnt(0) lgkmcnt(0)" ::: "memory");
    __builtin_amdgcn_sched_barrier(0);

    // ---- B duty (ALL 512 threads): thread owns (hw=brow, c-quad q).
    const int brow = tid & 63;
    const int q    = tid >> 6;             // 0..7 (c-quad)
    const int hwg  = hw0 + brow;
    const bool bvalid = hwg < HW;
    const float* xq = x + ((size_t)b * CIN + q * 4) * HW + hwg;
    const int bDstOff = brow * 64 + (((q >> 1) ^ ((brow >> 1) & 3)) * 16) + ((q & 1) * 8);
    char* bDstBase = (char*)Bs;

    // ---- A staging: 4 x 16B chunks/thread per kb from wT
    const char* aSrc = (const char*)wT + tid * 16;
    char* aDst = (char*)As + tid * 16;

    // per-thread invariant fragment byte-offsets
    int aOff[4], bOff[4];
    #pragma unroll
    for (int mf = 0; mf < 4; ++mf) {
        int r = wid * 64 + mf * 16 + lc;           // 0..511
        aOff[mf] = r * 64 + ((lg ^ ((r >> 1) & 3)) * 16);
    }
    #pragma unroll
    for (int nf = 0; nf < 4; ++nf) {
        int r = nf * 16 + lc;                      // 0..63
        bOff[nf] = r * 64 + ((lg ^ ((r >> 1) & 3)) * 16);
    }

    float regB[2][4];
    #pragma unroll
    for (int i = 0; i < 4; ++i) { regB[0][i] = 0.f; regB[1][i] = 0.f; }

    f32x4 acc[4][4];
    #pragma unroll
    for (int i = 0; i < 4; ++i)
        #pragma unroll
        for (int j = 0; j < 4; ++j)
            acc[i][j] = (f32x4){0.f, 0.f, 0.f, 0.f};

// stage s lives in reg set (s&1); all indices compile-time after unroll
#define BLOAD(SET, kb)                                                     \
    do {                                                                   \
        const float* src_ = xq + (size_t)(kb) * 32 * HW;                   \
        _Pragma("unroll")                                                  \
        for (int i_ = 0; i_ < 4; ++i_)                                     \
            regB[SET][i_] = bvalid ? src_[(size_t)i_ * HW] : 0.f;          \
    } while (0)

#define BWRITE(SET, buf)                                                   \
    do {                                                                   \
        bf16x4 o_;                                                         \
        _Pragma("unroll")                                                  \
        for (int i_ = 0; i_ < 4; ++i_) o_[i_] = f2bf(regB[SET][i_]);       \
        *(bf16x4*)(bDstBase + (buf) * 4096 + bDstOff) = o_;                \
    } while (0)

#define ALOAD(buf, kb)                                                     \
    do {                                                                   \
        _Pragma("unroll")                                                  \
        for (int l_ = 0; l_ < 4; ++l_)                                     \
            gl_lds16(aSrc + (size_t)(kb) * 32768 + l_ * 8192,              \
                     aDst + (buf) * 32768 + l_ * 8192);                    \
    } while (0)

    // ---- prologue
    BLOAD(0, 0);                  // queue: B0(4)
    ALOAD(0, 0);                  // queue: B0(4) A0(4)
    asm volatile("s_waitcnt vmcnt(4)" ::: "memory");   // B0 regs ready
    __builtin_amdgcn_sched_barrier(0);
    BWRITE(0, 0);
    BLOAD(1, 1);                  // queue: A0(4) B1(4)
    asm volatile("s_waitcnt vmcnt(4)" ::: "memory");   // A0 in LDS; B1 flying
    __builtin_amdgcn_sched_barrier(0);
    asm volatile("s_waitcnt lgkmcnt(0)" ::: "memory");
    __builtin_amdgcn_s_barrier();
    __builtin_amdgcn_sched_barrier(0);

    #pragma unroll
    for (int t = 0; t < 16; ++t) {
        const char* ab = (const char*)As + (t & 1) * 32768;
        const char* bb = (const char*)Bs + (t & 1) * 4096;

        bf16x8 aF[4], bF[4];
        #pragma unroll
        for (int mf = 0; mf < 4; ++mf) aF[mf] = *(const bf16x8*)(ab + aOff[mf]);
        #pragma unroll
        for (int nf = 0; nf < 4; ++nf) bF[nf] = *(const bf16x8*)(bb + bOff[nf]);

        if (t < 15) ALOAD((t + 1) & 1, t + 1);   // A depth-1 (L2-hot)
        if (t < 14) BLOAD(t & 1, t + 2);         // B depth-2 (HBM-deep)

        __builtin_amdgcn_s_setprio(1);
        #pragma unroll
        for (int mf = 0; mf < 4; ++mf)
            #pragma unroll
            for (int nf = 0; nf < 4; ++nf)
                acc[mf][nf] = __builtin_amdgcn_mfma_f32_16x16x32_bf16(
                    aF[mf], bF[nf], acc[mf][nf], 0, 0, 0);
        __builtin_amdgcn_s_setprio(0);

        if (t < 15) {
            if (t < 14) {
                // queue: B(t+1)4, A(t+1)4, B(t+2)4 -> leave only B(t+2)
                asm volatile("s_waitcnt vmcnt(4)" ::: "memory");
            } else {
                // queue: B(15)4, A(15)4
                asm volatile("s_waitcnt vmcnt(0)" ::: "memory");
            }
            __builtin_amdgcn_sched_barrier(0);
            BWRITE((t + 1) & 1, (t + 1) & 1);
            asm volatile("s_waitcnt lgkmcnt(0)" ::: "memory");
            __builtin_amdgcn_s_barrier();
            __builtin_amdgcn_sched_barrier(0);
        }
    }

    // ---- epilogue: barrier-free, waves independent
    if (wid < 4) {
        // conv1p rows 0..255: store pre-activation bf16
        #pragma unroll
        for (int mf = 0; mf < 4; ++mf) {
            int ch = wid * 64 + mf * 16 + lg * 4;
            #pragma unroll
            for (int nf = 0; nf < 4; ++nf) {
                int hw = hw0 + nf * 16 + lc;
                if (hw < HW) {
                    #pragma unroll
                    for (int j = 0; j < 4; ++j)
                        outp_pre[((size_t)(b * CP + ch + j)) * HW + hw] = f2bf(acc[mf][nf][j]);
                }
            }
        }
    } else {
        // conv1g rows: mish((acc+beta)*mask); intra-wave sum/max over 64 hw
        #pragma unroll
        for (int mf = 0; mf < 4; ++mf) {
            #pragma unroll
            for (int j = 0; j < 4; ++j) {
                int rloc = (wid - 4) * 64 + mf * 16 + lg * 4 + j;   // 0..255
                float beta = betaS[rloc];
                float s = 0.f, mx = -INFINITY;
                #pragma unroll
                for (int nf = 0; nf < 4; ++nf) {
                    int cl = nf * 16 + lc;
                    int hw = hw0 + cl;
                    float mv = maskS[cl];
                    float val = mish_f((acc[mf][nf][j] + beta) * mv);
                    if (hw < HW) {
                        s += val * mv;
                        mx = fmaxf(mx, val + mv - 1.f);
                    }
                }
                #pragma unroll
                for (int off = 1; off < 16; off <<= 1) {
                    s += __shfl_xor(s, off, 64);
                    mx = fmaxf(mx, __shfl_xor(mx, off, 64));
                }
                if (lc == 0) {
                    psum[((size_t)(b * CP + rloc)) * NT + n] = s;
                    pmax[((size_t)(b * CP + rloc)) * NT + n] = mx;
                }
            }
        }
    }
#undef BLOAD
#undef BWRITE
#undef ALOAD
}

// ---------------------------------------------------------------------------
// K2: per-batch pooled vector + linear_g. Grid 256 blocks x 256 threads.
// ---------------------------------------------------------------------------
__global__ __launch_bounds__(256) void k2_pool_linear(
    const float* __restrict__ mask, const float* __restrict__ psum,
    const float* __restrict__ pmax, const float* __restrict__ lw,
    float* __restrict__ g_out)
{
    int b = blockIdx.x, t = threadIdx.x;
    __shared__ float pooled[768];
    __shared__ float msr[4];

    float s = 0.f;
    for (int i = t; i < HW; i += 256) s += mask[b * HW + i];
    #pragma unroll
    for (int off = 1; off < 64; off <<= 1) s += __shfl_xor(s, off, 64);
    if ((t & 63) == 0) msr[t >> 6] = s;
    __syncthreads();
    float msum = msr[0] + msr[1] + msr[2] + msr[3];

    {
        int c = t;
        const float* ps = psum + (size_t)(b * CP + c) * NT;
        const float* pm = pmax + (size_t)(b * CP + c) * NT;
        float s3 = 0.f, m3 = -INFINITY;
        #pragma unroll
        for (int i = 0; i < NT; ++i) { s3 += ps[i]; m3 = fmaxf(m3, pm[i]); }
        float mean = s3 / msum;
        float sq = (sqrtf(msum) - 14.f) * 0.1f;
        pooled[c] = mean; pooled[256 + c] = mean * sq; pooled[512 + c] = m3;
    }
    __syncthreads();
    {
        int o = t;
        const float4* wrow = (const float4*)(lw + (size_t)o * 768);
        float acc = 0.f;
        #pragma unroll 8
        for (int j = 0; j < 192; ++j) {
            float4 w4 = wrow[j];
            float4 p4 = *(const float4*)&pooled[j * 4];
            acc += p4.x * w4.x + p4.y * w4.y + p4.z * w4.z + p4.w * w4.w;
        }
        g_out[b * CP + o] = acc;
    }
}

// ---------------------------------------------------------------------------
// K3: final fused mish((outp_pre+g+beta2)*mask) -> conv2p -> mask bias.
// outp_pre is bf16. Grid (6 hw-tiles, 256 b) x 256 threads.
// ---------------------------------------------------------------------------
__global__ __launch_bounds__(256) void k3_final(
    const short* __restrict__ outp_pre, const float* __restrict__ mask,
    const float* __restrict__ g_out, const float* __restrict__ beta2,
    const float* __restrict__ w2, float* __restrict__ out)
{
    int ht = blockIdx.x, b = blockIdx.y;
    int t = threadIdx.x;
    __shared__ float w2S[NOUT * 256];
    __shared__ float gbS[256];
    __shared__ float part[NOUT][256];

    for (int i = t; i < NOUT * 256; i += 256) w2S[i] = w2[i];
    gbS[t] = g_out[b * CP + t] + beta2[t];
    __syncthreads();

    int hw = t & 63, cg = t >> 6;
    int hwg = ht * 64 + hw;
    bool valid = hwg < HW;
    float maskv = valid ? mask[b * HW + hwg] : 0.f;

    float acc[NOUT] = {0.f, 0.f, 0.f, 0.f, 0.f, 0.f};
    const short* src = outp_pre + ((size_t)(b * CP + cg * 64)) * HW + hwg;
    #pragma unroll 4
    for (int ci = 0; ci < 64; ++ci) {
        float v = valid ? bf2f(src[(size_t)ci * HW]) : 0.f;
        float mm = mish_f((v + gbS[cg * 64 + ci]) * maskv);
        #pragma unroll
        for (int o = 0; o < NOUT; ++o) acc[o] += mm * w2S[o * 256 + cg * 64 + ci];
    }
    #pragma unroll
    for (int o = 0; o < NOUT; ++o) part[o][t] = acc[o];
    __syncthreads();

    for (int idx = t; idx < NOUT * 64; idx += 256) {
        int o = idx >> 6, h2 = idx & 63;
        int hg = ht * 64 + h2;
        if (hg < HW) {
            float mv = mask[b * HW + hg];
            float sum = part[o][h2] + part[o][64 + h2] + part[o][128 + h2] + part[o][192 + h2];
            out[((size_t)(b * NOUT + o)) * HW + hg] = sum - (1.f - mv) * 5000.f;
        }
    }
}

extern "C" void kernel_launch(void* const* d_in, const int* in_sizes, int n_in,
                              void* d_out, int out_size, void* d_ws, size_t ws_size,
                              hipStream_t stream) {
    const float* x     = (const float*)d_in[0];
    const float* mask  = (const float*)d_in[1];
    const float* w1p   = (const float*)d_in[2];
    const float* w1g   = (const float*)d_in[3];
    const float* betag = (const float*)d_in[4];
    const float* lw    = (const float*)d_in[5];
    const float* beta2 = (const float*)d_in[6];
    const float* w2    = (const float*)d_in[7];
    float* out = (float*)d_out;

    char* ws = (char*)d_ws;
    short* outp_pre = (short*)(ws);                      // 256*256*361*2 = 47,316,992 B
    short* wT       = (short*)(ws + 47316992);           // 16*32768      =     524,288 B
    float* psum     = (float*)(ws + 47841280);           // 256*256*6*4   =   1,572,864 B
    float* pmax     = (float*)(ws + 49414144);           // 256*256*6*4   =   1,572,864 B
    float* g_out    = (float*)(ws + 50987008);           // 256*256*4     =     262,144 B

    hipLaunchKernelGGL(k0_weights, dim3(128), dim3(256), 0, stream, w1p, w1g, wT);
    hipLaunchKernelGGL(k1_conv1, dim3(1536), dim3(512), 0, stream,
                       x, wT, mask, betag, outp_pre, psum, pmax);
    hipLaunchKernelGGL(k2_pool_linear, dim3(BATCH), dim3(256), 0, stream,
                       mask, psum, pmax, lw, g_out);
    hipLaunchKernelGGL(k3_final, dim3(6, BATCH), dim3(256), 0, stream,
                       outp_pre, mask, g_out, beta2, w2, out);
    (void)in_sizes; (void)n_in; (void)out_size; (void)ws_size;
}